// Round 8
// baseline (1339.914 us; speedup 1.0000x reference)
//
#include <hip/hip_runtime.h>
#include <math.h>

#define NTOK 13824            // 24*24*24
#define MTOT 27648            // B*NTOK
#define BATCH 2
#define CIN 128
#define DMODEL 256
#define NHEAD 8
#define NLAYERS 4
#define DFF 512
#define NSPLIT 27
#define KVHALF ((size_t)BATCH * 256 * NTOK)

typedef float f32x4 __attribute__((ext_vector_type(4)));
typedef __bf16 bf16x8 __attribute__((ext_vector_type(8)));

__device__ __forceinline__ unsigned short f2bf(float f) {
    unsigned u = __float_as_uint(f);
    return (unsigned short)((u + 0x7FFFu + ((u >> 16) & 1u)) >> 16);
}
__device__ __forceinline__ float bf2f(unsigned short h) {
    return __uint_as_float(((unsigned)h) << 16);
}

// ---------------------------------------------------------------------------
// Direct-fragment bf16 MFMA GEMM (no LDS, no barriers).
// C[M x N] = act(A[M x K] * B[K x N] + bias), B given transposed Bt[N][K].
// 128x128 tile, 4 waves (2x2), wave = 64x64 via 4x4 MFMA grid.
// Fragments loaded straight from global (lane fm = free-dim row, fq = k-chunk)
// -> compiler pipelines with fine vmcnt, ctx_mfma-style.
// SWAPPED mfma(b,a): lane holds col m = i*16+fm, rows n = j*16+fq*4+r
// -> packed 8B/16B stores.
// ACT: 0 none, 1 relu, 2 gelu(exact). OUTM: 1 bf16 only, 2 f32+bf16.
// QSM: fused q-softmax over 32-col head groups (writes exp/sum).
// KC = K/32 (compile-time).
// ---------------------------------------------------------------------------
template<int ACT, int OUTM, int QSM, int KC>
__global__ __launch_bounds__(256) void gemm_direct(
    const unsigned short* __restrict__ A, int lda,
    const unsigned short* __restrict__ Bt, int ldb,
    const float* __restrict__ bias,
    float* __restrict__ Cf, unsigned short* __restrict__ Cb,
    int ldc, long sA, long sB, long sC)
{
    A  += (size_t)blockIdx.z * sA;
    Bt += (size_t)blockIdx.z * sB;
    if (OUTM == 2) Cf += (size_t)blockIdx.z * sC;
    Cb += (size_t)blockIdx.z * sC;

    const int t = threadIdx.x, lane = t & 63, wave = t >> 6;
    const int wm = wave & 1, wn = wave >> 1;
    const int m0 = blockIdx.x * 128 + wm * 64;
    const int n0 = blockIdx.y * 128 + wn * 64;
    const int fm = lane & 15, fq = lane >> 4;
    const int ko = fq * 8;

    const unsigned short* pa = A  + (size_t)(m0 + fm) * lda + ko;
    const unsigned short* pb = Bt + (size_t)(n0 + fm) * ldb + ko;

    f32x4 acc[4][4];
    #pragma unroll
    for (int i = 0; i < 4; ++i)
        #pragma unroll
        for (int j = 0; j < 4; ++j) acc[i][j] = (f32x4)0.0f;

    #pragma unroll 4
    for (int s = 0; s < KC; ++s) {
        const int k0 = s * 32;
        bf16x8 af[4], bg[4];
        #pragma unroll
        for (int i = 0; i < 4; ++i) {
            const uint4 r4 = *(const uint4*)(pa + (size_t)i * 16 * lda + k0);
            af[i] = *(const bf16x8*)&r4;
        }
        #pragma unroll
        for (int j = 0; j < 4; ++j) {
            const uint4 r4 = *(const uint4*)(pb + (size_t)j * 16 * ldb + k0);
            bg[j] = *(const bf16x8*)&r4;
        }
        #pragma unroll
        for (int i = 0; i < 4; ++i)
            #pragma unroll
            for (int j = 0; j < 4; ++j)
                acc[i][j] = __builtin_amdgcn_mfma_f32_16x16x32_bf16(
                    bg[j], af[i], acc[i][j], 0, 0, 0);
    }

    const int fq4 = fq * 4;
    #pragma unroll
    for (int i = 0; i < 4; ++i) {
        const int m = m0 + i * 16 + fm;
        float v[4][4];
        #pragma unroll
        for (int j = 0; j < 4; ++j) {
            const float4 b4 = *(const float4*)(bias + n0 + j * 16 + fq4);
            v[j][0] = acc[i][j][0] + b4.x;
            v[j][1] = acc[i][j][1] + b4.y;
            v[j][2] = acc[i][j][2] + b4.z;
            v[j][3] = acc[i][j][3] + b4.w;
            if (ACT == 1) {
                #pragma unroll
                for (int r = 0; r < 4; ++r) v[j][r] = fmaxf(v[j][r], 0.0f);
            }
            if (ACT == 2) {
                #pragma unroll
                for (int r = 0; r < 4; ++r)
                    v[j][r] = 0.5f * v[j][r] *
                              (1.0f + erff(v[j][r] * 0.7071067811865476f));
            }
        }
        if (QSM) {
            #pragma unroll
            for (int g = 0; g < 2; ++g) {
                float mx = -1e30f;
                #pragma unroll
                for (int j = 2 * g; j < 2 * g + 2; ++j)
                    #pragma unroll
                    for (int r = 0; r < 4; ++r) mx = fmaxf(mx, v[j][r]);
                mx = fmaxf(mx, __shfl_xor(mx, 16, 64));
                mx = fmaxf(mx, __shfl_xor(mx, 32, 64));
                float s = 0.0f;
                #pragma unroll
                for (int j = 2 * g; j < 2 * g + 2; ++j)
                    #pragma unroll
                    for (int r = 0; r < 4; ++r) {
                        v[j][r] = __expf(v[j][r] - mx);
                        s += v[j][r];
                    }
                s += __shfl_xor(s, 16, 64);
                s += __shfl_xor(s, 32, 64);
                const float rs = 1.0f / s;
                #pragma unroll
                for (int j = 2 * g; j < 2 * g + 2; ++j)
                    #pragma unroll
                    for (int r = 0; r < 4; ++r) v[j][r] *= rs;
            }
        }
        #pragma unroll
        for (int j = 0; j < 4; ++j) {
            const size_t off = (size_t)m * ldc + n0 + j * 16 + fq4;
            if (OUTM == 2) {
                float4 o4;
                o4.x = v[j][0]; o4.y = v[j][1]; o4.z = v[j][2]; o4.w = v[j][3];
                *(float4*)(Cf + off) = o4;
            }
            ushort4 u4;
            u4.x = f2bf(v[j][0]); u4.y = f2bf(v[j][1]);
            u4.z = f2bf(v[j][2]); u4.w = f2bf(v[j][3]);
            *(ushort4*)(Cb + off) = u4;
        }
    }
}

// ---------------------------------------------------------------------------
// one-shot weight conversion: transpose to [N][K] bf16 + bias concat
// ---------------------------------------------------------------------------
#define CW_QKV  786432   // 4*768*256
#define CW_O   1048576   // + 4*256*256
#define CW_1   1572864   // + 4*512*256
#define CW_2   2097152   // + 4*256*512
#define CW_X   2129920   // + 256*128
#define CW_B   2132992   // + 4*768
__global__ __launch_bounds__(256) void conv_weights(
    const float* __restrict__ Wq, const float* __restrict__ Wk,
    const float* __restrict__ Wv, const float* __restrict__ Wo,
    const float* __restrict__ fw1, const float* __restrict__ fw2,
    const float* __restrict__ Wx_w,
    const float* __restrict__ bq, const float* __restrict__ bk,
    const float* __restrict__ bv,
    unsigned short* __restrict__ wqkv_t, unsigned short* __restrict__ wo_t,
    unsigned short* __restrict__ w1_t, unsigned short* __restrict__ w2_t,
    unsigned short* __restrict__ wx_bf, float* __restrict__ bqkv)
{
    const int e = blockIdx.x * 256 + threadIdx.x;
    if (e < CW_QKV) {
        const int i = e / 196608, r = e % 196608;
        const int n = r / 256, k = r % 256;
        const float* src = (n < 256) ? Wq : (n < 512) ? Wk : Wv;
        wqkv_t[e] = f2bf(src[((size_t)i * 256 + k) * 256 + (n & 255)]);
    } else if (e < CW_O) {
        const int r = e - CW_QKV;
        const int i = r / 65536, rr = r % 65536, n = rr / 256, k = rr % 256;
        wo_t[r] = f2bf(Wo[((size_t)i * 256 + k) * 256 + n]);
    } else if (e < CW_1) {
        const int r = e - CW_O;
        const int i = r / 131072, rr = r % 131072, n = rr / 256, k = rr % 256;
        w1_t[r] = f2bf(fw1[((size_t)i * 256 + k) * 512 + n]);
    } else if (e < CW_2) {
        const int r = e - CW_1;
        const int i = r / 131072, rr = r % 131072, n = rr / 512, k = rr % 512;
        w2_t[r] = f2bf(fw2[((size_t)i * 512 + k) * 256 + n]);
    } else if (e < CW_X) {
        const int r = e - CW_2;
        wx_bf[r] = f2bf(Wx_w[r]);     // Wx_w [out][in] is already B^T layout
    } else if (e < CW_B) {
        const int r = e - CW_X;
        const int i = r / 768, j = r % 768;
        const float v = (j < 256) ? bq[i * 256 + j]
                      : (j < 512) ? bk[i * 256 + j - 256]
                                  : bv[i * 256 + j - 512];
        bqkv[r] = v;
    }
}

// ---------------------------------------------------------------------------
// x [B][CIN][NTOK] f32 -> xbf [(b,n)][CIN] bf16, LDS 32x32 tile transpose.
// ---------------------------------------------------------------------------
__global__ __launch_bounds__(256) void conv_x(
    const float* __restrict__ x, unsigned short* __restrict__ xbf)
{
    __shared__ float tile[32][33];
    const int n0 = blockIdx.x * 32;
    const int c0 = blockIdx.y * 32;
    const int b  = blockIdx.z;
    const int t = threadIdx.x;
    const int tn = t & 31, tc = t >> 5;
    #pragma unroll
    for (int p = 0; p < 4; ++p)
        tile[tc + p * 8][tn] =
            x[((size_t)(b * CIN + c0 + tc + p * 8)) * NTOK + n0 + tn];
    __syncthreads();
    const int cc = t & 31, nr = t >> 5;
    #pragma unroll
    for (int p = 0; p < 4; ++p)
        xbf[((size_t)(b * NTOK + n0 + nr + p * 8)) * CIN + c0 + cc] =
            f2bf(tile[cc][nr + p * 8]);
}

// ---------------------------------------------------------------------------
// kvt: qkv k,v slots -> expkT/vT [b][ch][tok] bf16 (exp applied to k).
// ---------------------------------------------------------------------------
__global__ __launch_bounds__(256) void kvt_kernel(
    const unsigned short* __restrict__ qkv, unsigned short* __restrict__ kvT)
{
    const int nb = blockIdx.x, h = blockIdx.y, b = blockIdx.z;
    const int n0 = nb * 64;
    const int t = threadIdx.x;
    __shared__ __attribute__((aligned(16))) unsigned short LT[64 * 72];
    const int tl = t >> 2, cg = t & 3;
    const unsigned short* src =
        qkv + ((size_t)(b * NTOK + n0 + tl)) * 768 + 256 + h * 32 + cg * 8;
    const uint4 kr = *(const uint4*)src;
    const uint4 vr = *(const uint4*)(src + 256);
    const unsigned short* ks = (const unsigned short*)&kr;
    const unsigned short* vs = (const unsigned short*)&vr;
    #pragma unroll
    for (int j = 0; j < 8; ++j) {
        const int ch = cg * 8 + j;
        LT[ch * 72 + tl]        = f2bf(__expf(bf2f(ks[j])));
        LT[(32 + ch) * 72 + tl] = vs[j];
    }
    __syncthreads();
    #pragma unroll
    for (int it = 0; it < 2; ++it) {
        const int idx = it * 256 + t;       // 0..511
        const int row = idx >> 3, seg = idx & 7;
        const uint4 val = *(const uint4*)(LT + row * 72 + seg * 8);
        const int ch = row & 31;
        const size_t dst = ((row >= 32) ? KVHALF : (size_t)0)
                         + ((size_t)(b * 256 + h * 32 + ch)) * NTOK + n0 + seg * 8;
        *(uint4*)(kvT + dst) = val;
    }
}

// ---------------------------------------------------------------------------
// ctx via MFMA, split-K, no atomics.
// ---------------------------------------------------------------------------
__global__ __launch_bounds__(256) void ctx_mfma(
    const unsigned short* __restrict__ kvT,
    float* __restrict__ ctxp, float* __restrict__ skp)
{
    const int s = blockIdx.x, h = blockIdx.y, b = blockIdx.z;
    const int t = threadIdx.x, w = t >> 6, l = t & 63;
    const int fm = l & 15, fq = (l >> 4) * 8;
    const size_t rowA = (size_t)(b * 256 + h * 32 + fm) * NTOK;
    const int n0 = s * 512 + w * 128 + fq;
    const unsigned short* pa = kvT + rowA + n0;
    const unsigned short* pb = kvT + KVHALF + rowA + n0;

    f32x4 acc[2][2];
    #pragma unroll
    for (int x = 0; x < 2; ++x)
        #pragma unroll
        for (int y = 0; y < 2; ++y) acc[x][y] = (f32x4)0.0f;
    float ss0 = 0.0f, ss1 = 0.0f;

    #pragma unroll
    for (int step = 0; step < 4; ++step) {
        const int ko = step * 32;
        const uint4 ra0 = *(const uint4*)(pa + ko);
        const uint4 ra1 = *(const uint4*)(pa + (size_t)16 * NTOK + ko);
        const uint4 rb0 = *(const uint4*)(pb + ko);
        const uint4 rb1 = *(const uint4*)(pb + (size_t)16 * NTOK + ko);
        const bf16x8 a0 = *(const bf16x8*)&ra0;
        const bf16x8 a1 = *(const bf16x8*)&ra1;
        const bf16x8 b0 = *(const bf16x8*)&rb0;
        const bf16x8 b1 = *(const bf16x8*)&rb1;
        acc[0][0] = __builtin_amdgcn_mfma_f32_16x16x32_bf16(a0, b0, acc[0][0], 0, 0, 0);
        acc[0][1] = __builtin_amdgcn_mfma_f32_16x16x32_bf16(a0, b1, acc[0][1], 0, 0, 0);
        acc[1][0] = __builtin_amdgcn_mfma_f32_16x16x32_bf16(a1, b0, acc[1][0], 0, 0, 0);
        acc[1][1] = __builtin_amdgcn_mfma_f32_16x16x32_bf16(a1, b1, acc[1][1], 0, 0, 0);
        const unsigned short* u0 = (const unsigned short*)&ra0;
        const unsigned short* u1 = (const unsigned short*)&ra1;
        #pragma unroll
        for (int j = 0; j < 8; ++j) { ss0 += bf2f(u0[j]); ss1 += bf2f(u1[j]); }
    }

    ss0 += __shfl_xor(ss0, 16, 64); ss0 += __shfl_xor(ss0, 32, 64);
    ss1 += __shfl_xor(ss1, 16, 64); ss1 += __shfl_xor(ss1, 32, 64);
    __shared__ float skw[4][32];
    __shared__ float redc[4][32][33];
    if (l < 16) { skw[w][fm] = ss0; skw[w][16 + fm] = ss1; }

    const int rb4 = (l >> 4) * 4;
    #pragma unroll
    for (int x = 0; x < 2; ++x)
        #pragma unroll
        for (int y = 0; y < 2; ++y)
            #pragma unroll
            for (int r = 0; r < 4; ++r)
                redc[w][x * 16 + rb4 + r][y * 16 + fm] = acc[x][y][r];
    __syncthreads();

    if (t < 32)
        skp[(size_t)s * 512 + b * 256 + h * 32 + t] =
            skw[0][t] + skw[1][t] + skw[2][t] + skw[3][t];

    const int e0 = t * 4;
    const int dd = e0 >> 5, c0 = e0 & 31;
    float4 o;
    o.x = redc[0][dd][c0+0] + redc[1][dd][c0+0] + redc[2][dd][c0+0] + redc[3][dd][c0+0];
    o.y = redc[0][dd][c0+1] + redc[1][dd][c0+1] + redc[2][dd][c0+1] + redc[3][dd][c0+1];
    o.z = redc[0][dd][c0+2] + redc[1][dd][c0+2] + redc[2][dd][c0+2] + redc[3][dd][c0+2];
    o.w = redc[0][dd][c0+3] + redc[1][dd][c0+3] + redc[2][dd][c0+3] + redc[3][dd][c0+3];
    *(float4*)(ctxp + ((size_t)s * 16 + b * 8 + h) * 1024 + e0) = o;
}

// reduce split-K partials: ctx[16][1024] and Sk[512]. grid 66 x 256.
__global__ __launch_bounds__(256) void ctxred(
    const float* __restrict__ ctxp, const float* __restrict__ skp,
    float* __restrict__ ctx, float* __restrict__ Sk)
{
    const int o = blockIdx.x * 256 + threadIdx.x;   // 0..16895
    if (o < 16384) {
        float a = 0.0f;
        for (int s = 0; s < NSPLIT; ++s) a += ctxp[(size_t)s * 16384 + o];
        ctx[o] = a;
    } else {
        const int c = o - 16384;
        float a = 0.0f;
        for (int s = 0; s < NSPLIT; ++s) a += skp[(size_t)s * 512 + c];
        Sk[c] = a;
    }
}

// ---------------------------------------------------------------------------
// W'[b][n][h*32+d] = (1/sqrt(dk)) * (1/Sk[d]) * sum_e ctx[b][h][d][e] * Wo[h*32+e][n]
// ---------------------------------------------------------------------------
__global__ __launch_bounds__(256) void ctxwo_kernel(
    const float* __restrict__ ctx, const float* __restrict__ Sk,
    const unsigned short* __restrict__ wo_t, unsigned short* __restrict__ wp)
{
    const int h = blockIdx.x, b = blockIdx.y;
    const int n = threadIdx.x;
    __shared__ float cl[1024];
    __shared__ float sdk[32];
    {
        const float* cp = ctx + (size_t)(b * 8 + h) * 1024;
        *(float4*)&cl[n * 4] = *(const float4*)&cp[n * 4];
    }
    if (n < 32) sdk[n] = 0.17677669529663687f / Sk[b * 256 + h * 32 + n];
    __syncthreads();
    float w[32];
    const unsigned short* wop = wo_t + (size_t)n * 256 + h * 32;
    #pragma unroll
    for (int e = 0; e < 32; ++e) w[e] = bf2f(wop[e]);
    unsigned short outv[32];
    #pragma unroll
    for (int d = 0; d < 32; ++d) {
        float acc = 0.0f;
        #pragma unroll
        for (int e = 0; e < 32; ++e) acc += cl[d * 32 + e] * w[e];
        outv[d] = f2bf(acc * sdk[d]);
    }
    unsigned short* op = wp + (size_t)b * 65536 + (size_t)n * 256 + h * 32;
    #pragma unroll
    for (int d = 0; d < 32; d += 8)
        *(uint4*)(op + d) = *(uint4*)(outv + d);
}

// ---------------------------------------------------------------------------
// t = LayerNorm(t + add(bf16)); writes t f32 in place (+ optional bf16 copy)
// ---------------------------------------------------------------------------
template<int WB>
__global__ __launch_bounds__(256) void ln_kernel(
    float* __restrict__ t, const unsigned short* __restrict__ add,
    const float* __restrict__ g, const float* __restrict__ bta,
    unsigned short* __restrict__ tbf)
{
    const int row = blockIdx.x;
    const int c = threadIdx.x;
    const int lane = c & 63, wave = c >> 6;
    const size_t off = (size_t)row * 256 + c;
    const float v = t[off] + bf2f(add[off]);
    __shared__ float red[8];
    float s = v;
    #pragma unroll
    for (int o = 32; o; o >>= 1) s += __shfl_xor(s, o, 64);
    if (lane == 0) red[wave] = s;
    __syncthreads();
    const float mu = (red[0] + red[1] + red[2] + red[3]) * (1.0f / 256.0f);
    const float dv = v - mu;
    float s2 = dv * dv;
    #pragma unroll
    for (int o = 32; o; o >>= 1) s2 += __shfl_xor(s2, o, 64);
    if (lane == 0) red[wave + 4] = s2;
    __syncthreads();
    const float var = (red[4] + red[5] + red[6] + red[7]) * (1.0f / 256.0f);
    const float o = dv * rsqrtf(var + 1e-6f) * g[c] + bta[c];
    t[off] = o;
    if (WB) tbf[off] = f2bf(o);
}

// ---------------------------------------------------------------------------
// depthwise 3x3x3 conv + residual, register-resident weights + sliding window.
// ---------------------------------------------------------------------------
template<int WB>
__global__ __launch_bounds__(256) void posconv_kernel(
    const float* __restrict__ tin, const float* __restrict__ pw,
    const float* __restrict__ pb, float* __restrict__ outp,
    unsigned short* __restrict__ tbfp)
{
    const int hw = blockIdx.x;            // 0..575
    const int b  = blockIdx.y;
    const int hh = hw / 24, ww = hw % 24;
    const int c  = threadIdx.x;

    float w[27];
    #pragma unroll
    for (int k = 0; k < 27; ++k) w[k] = pw[c * 27 + k];
    const float bias = pb[c];

    const float* base = tin + (size_t)b * NTOK * 256 + c;

    const float* colp[9];
    bool colok[9];
    #pragma unroll
    for (int dh = -1; dh <= 1; ++dh)
        #pragma unroll
        for (int dw = -1; dw <= 1; ++dw) {
            const int j = (dh + 1) * 3 + (dw + 1);
            const int h2 = hh + dh, w2 = ww + dw;
            colok[j] = ((unsigned)h2 < 24u) & ((unsigned)w2 < 24u);
            colp[j] = base + (size_t)((h2 * 24 + w2) * 24) * 256;
        }

    float win[9][3];
    #pragma unroll
    for (int j = 0; j < 9; ++j) {
        win[j][0] = 0.0f;
        win[j][1] = colok[j] ? colp[j][0] : 0.0f;
    }

    float* ob = outp + ((size_t)b * NTOK + (size_t)hw * 24) * 256 + c;
    unsigned short* tb = WB ? (tbfp + ((size_t)b * NTOK + (size_t)hw * 24) * 256 + c)
                            : (unsigned short*)nullptr;

    for (int d = 0; d < 24; ++d) {
        #pragma unroll
        for (int j = 0; j < 9; ++j)
            win[j][2] = (colok[j] && d < 23) ? colp[j][(d + 1) * 256] : 0.0f;

        float acc = bias + win[4][1];
        #pragma unroll
        for (int j = 0; j < 9; ++j) {
            acc += w[j * 3 + 0] * win[j][0];
            acc += w[j * 3 + 1] * win[j][1];
            acc += w[j * 3 + 2] * win[j][2];
        }
        ob[d * 256] = acc;
        if (WB) tb[d * 256] = f2bf(acc);

        #pragma unroll
        for (int j = 0; j < 9; ++j) { win[j][0] = win[j][1]; win[j][1] = win[j][2]; }
    }
}

// ---------------------------------------------------------------------------
// final transpose: t [MTOT][256] f32 -> out [B][256][NTOK] (LDS tiled)
// ---------------------------------------------------------------------------
__global__ __launch_bounds__(256) void tr_out(
    const float* __restrict__ tin, float* __restrict__ outp)
{
    __shared__ float tile[32][33];
    const int m0 = blockIdx.x * 32;
    const int c0 = blockIdx.y * 32;
    const int t = threadIdx.x;
    const int tc = t & 31, tr = t >> 5;
    #pragma unroll
    for (int r = 0; r < 4; ++r)
        tile[tr + r * 8][tc] = tin[(size_t)(m0 + tr + r * 8) * 256 + c0 + tc];
    __syncthreads();
    const int b = (m0 >= NTOK) ? 1 : 0;
    const int n0 = m0 - b * NTOK;
    #pragma unroll
    for (int r = 0; r < 4; ++r)
        outp[((size_t)b * 256 + c0 + tr + r * 8) * NTOK + n0 + tc] = tile[tc][tr + r * 8];
}

// ---------------------------------------------------------------------------
// launch
// ---------------------------------------------------------------------------
extern "C" void kernel_launch(void* const* d_in, const int* in_sizes, int n_in,
                              void* d_out, int out_size, void* d_ws, size_t ws_size,
                              hipStream_t stream)
{
    (void)in_sizes; (void)n_in; (void)out_size; (void)ws_size;
    const float* x     = (const float*)d_in[0];
    const float* Wx_w  = (const float*)d_in[1];
    const float* Wx_b  = (const float*)d_in[2];
    const float* Wq    = (const float*)d_in[3];
    const float* bq    = (const float*)d_in[4];
    const float* Wk    = (const float*)d_in[5];
    const float* bk    = (const float*)d_in[6];
    const float* Wv    = (const float*)d_in[7];
    const float* bv    = (const float*)d_in[8];
    const float* Wo    = (const float*)d_in[9];
    const float* bo    = (const float*)d_in[10];
    const float* ln1_g = (const float*)d_in[11];
    const float* ln1_b = (const float*)d_in[12];
    const float* ln2_g = (const float*)d_in[13];
    const float* ln2_b = (const float*)d_in[14];
    const float* fw1   = (const float*)d_in[15];
    const float* fb1   = (const float*)d_in[16];
    const float* fw2   = (const float*)d_in[17];
    const float* fb2   = (const float*)d_in[18];
    const float* pw    = (const float*)d_in[19];
    const float* pb    = (const float*)d_in[20];
    float* out = (float*)d_out;

    char* p = (char*)d_ws;
    float* tA            = (float*)p;          p += (size_t)MTOT * 256 * 4;
    float* tB            = (float*)p;          p += (size_t)MTOT * 256 * 4;
    unsigned short* tbf  = (unsigned short*)p; p += (size_t)MTOT * 256 * 2;
    unsigned short* qkv  = (unsigned short*)p; p += (size_t)MTOT * 768 * 2;
    unsigned short* hbf  = (unsigned short*)p; p += (size_t)MTOT * 512 * 2;   // also kvT
    unsigned short* ob   = (unsigned short*)p; p += (size_t)MTOT * 256 * 2;
    unsigned short* xbf  = (unsigned short*)p; p += (size_t)MTOT * 128 * 2;
    unsigned short* wqkv_t = (unsigned short*)p; p += (size_t)786432 * 2;
    unsigned short* wo_t   = (unsigned short*)p; p += (size_t)262144 * 2;
    unsigned short* w1_t   = (unsigned short*)p; p += (size_t)524288 * 2;
    unsigned short* w2_t   = (unsigned short*)p; p += (size_t)524288 * 2;
    unsigned short* wx_bf  = (unsigned short*)p; p += (size_t)32768 * 2;
    unsigned short* wp     = (unsigned short*)p; p += (size_t)BATCH * 65536 * 2;
    float* bqkv = (float*)p; p += 3072 * 4;
    float* ctx  = (float*)p; p += 16384 * 4;
    float* Sk   = (float*)p; p += 512 * 4;
    float* ctxp = (float*)p; p += (size_t)NSPLIT * 16384 * 4;
    float* skp  = (float*)p; p += (size_t)NSPLIT * 512 * 4;
    unsigned short* kvT = hbf;   // overlays FFN hidden (disjoint lifetime)

    hipLaunchKernelGGL(conv_weights, dim3(8333), dim3(256), 0, stream,
                       Wq, Wk, Wv, Wo, fw1, fw2, Wx_w, bq, bk, bv,
                       wqkv_t, wo_t, w1_t, w2_t, wx_bf, bqkv);
    hipLaunchKernelGGL(conv_x, dim3(NTOK / 32, CIN / 32, BATCH), dim3(256), 0, stream,
                       x, xbf);

    // input 1x1x1 conv + relu -> tA f32 + tbf bf16 (K=128)
    hipLaunchKernelGGL((gemm_direct<1, 2, 0, 4>), dim3(216, 2, 1), dim3(256), 0, stream,
                       xbf, CIN, wx_bf, CIN, Wx_b, tA, tbf, 256,
                       (long)0, (long)0, (long)0);

    for (int i = 0; i < NLAYERS; ++i) {
        float* tin  = (i & 1) ? tB : tA;
        float* tout = (i & 1) ? tA : tB;

        // QKV q-part with fused q-softmax (cols 0..255)
        hipLaunchKernelGGL((gemm_direct<0, 1, 1, 8>), dim3(216, 2, 1), dim3(256), 0, stream,
                           tbf, 256, wqkv_t + (size_t)i * 196608, 256,
                           bqkv + i * 768, nullptr, qkv, 768,
                           (long)0, (long)0, (long)0);
        // QKV k,v-part (cols 256..767)
        hipLaunchKernelGGL((gemm_direct<0, 1, 0, 8>), dim3(216, 4, 1), dim3(256), 0, stream,
                           tbf, 256, wqkv_t + (size_t)i * 196608 + 65536, 256,
                           bqkv + i * 768 + 256, nullptr, qkv + 256, 768,
                           (long)0, (long)0, (long)0);

        // ctx path: transpose -> MFMA split-K -> reduce
        hipLaunchKernelGGL(kvt_kernel, dim3(NTOK / 64, NHEAD, BATCH), dim3(256), 0, stream,
                           qkv, kvT);
        hipLaunchKernelGGL(ctx_mfma, dim3(NSPLIT, NHEAD, BATCH), dim3(256), 0, stream,
                           kvT, ctxp, skp);
        hipLaunchKernelGGL(ctxred, dim3(66), dim3(256), 0, stream, ctxp, skp, ctx, Sk);

        // W' = (ctx/Sk) @ Wo (per batch)
        hipLaunchKernelGGL(ctxwo_kernel, dim3(NHEAD, BATCH), dim3(256), 0, stream,
                           ctx, Sk, wo_t + (size_t)i * 65536, wp);

        // o_proj = qs @ W' + bo  (batched over z)
        hipLaunchKernelGGL((gemm_direct<0, 1, 0, 8>), dim3(108, 2, BATCH), dim3(256), 0, stream,
                           qkv, 768, wp, 256, bo + i * 256, nullptr, ob, 256,
                           (long)NTOK * 768, (long)65536, (long)NTOK * 256);

        hipLaunchKernelGGL((ln_kernel<1>), dim3(MTOT), dim3(256), 0, stream,
                           tin, ob, ln1_g + i * 256, ln1_b + i * 256, tbf);

        // FFN (hbf free again: kvT consumed)
        hipLaunchKernelGGL((gemm_direct<2, 1, 0, 8>), dim3(216, 4, 1), dim3(256), 0, stream,
                           tbf, 256, w1_t + (size_t)i * 131072, 256,
                           fb1 + i * 512, nullptr, hbf, 512,
                           (long)0, (long)0, (long)0);
        hipLaunchKernelGGL((gemm_direct<0, 1, 0, 16>), dim3(216, 2, 1), dim3(256), 0, stream,
                           hbf, 512, w2_t + (size_t)i * 131072, 512,
                           fb2 + i * 256, nullptr, ob, 256,
                           (long)0, (long)0, (long)0);
        hipLaunchKernelGGL((ln_kernel<0>), dim3(MTOT), dim3(256), 0, stream,
                           tin, ob, ln2_g + i * 256, ln2_b + i * 256, nullptr);

        // depthwise conv + residual -> tout f32 (+ tbf bf16 except last layer)
        if (i < NLAYERS - 1)
            hipLaunchKernelGGL((posconv_kernel<1>), dim3(576, BATCH), dim3(256), 0, stream,
                               tin, pw + (size_t)i * 6912, pb + i * 256, tout, tbf);
        else
            hipLaunchKernelGGL((posconv_kernel<0>), dim3(576, BATCH), dim3(256), 0, stream,
                               tin, pw + (size_t)i * 6912, pb + i * 256, tout, nullptr);
    }

    // layer 3 wrote tA
    hipLaunchKernelGGL(tr_out, dim3(MTOT / 32, 8), dim3(256), 0, stream, tA, out);
}

// Round 9
// 1030.099 us; speedup vs baseline: 1.3008x; 1.3008x over previous
//
#include <hip/hip_runtime.h>
#include <math.h>

#define NTOK 13824            // 24*24*24
#define MTOT 27648            // B*NTOK
#define BATCH 2
#define CIN 128
#define DMODEL 256
#define NHEAD 8
#define NLAYERS 4
#define DFF 512
#define NSPLIT 27
#define KVHALF ((size_t)BATCH * 256 * NTOK)

typedef float f32x4 __attribute__((ext_vector_type(4)));
typedef __bf16 bf16x8 __attribute__((ext_vector_type(8)));
typedef __attribute__((address_space(1))) void gvoid;
typedef __attribute__((address_space(3))) void lvoid;

__device__ __forceinline__ unsigned short f2bf(float f) {
    unsigned u = __float_as_uint(f);
    return (unsigned short)((u + 0x7FFFu + ((u >> 16) & 1u)) >> 16);
}
__device__ __forceinline__ float bf2f(unsigned short h) {
    return __uint_as_float(((unsigned)h) << 16);
}

// ---------------------------------------------------------------------------
// Hybrid bf16 MFMA GEMM: A staged in LDS for the WHOLE K (1 barrier per
// 256-K pass), B fragments direct from global (small weight tile, L2-hot).
// K-loop is barrier-free -> compiler pipelines with fine vmcnt.
// C[M x N] = act(A[M x K] * Bt[N][K]^T + bias). 128x128 tile, 4 waves (2x2).
// A LDS layout: [row][chunk] with chunk XOR-swizzle (chunk ^= row&7) so
// ds_read_b128 across fm-lanes is 2-way (free). Staging gathers the swizzled
// global chunk so GLDS16's forced lane-linear dest still lands correctly.
// Swapped mfma(b,a): lane holds col m, rows n -> packed stores.
// ACT: 0 none, 1 relu, 2 gelu. OUTM: 1 bf16, 2 f32+bf16. QSM: fused
// q-softmax over 32-col head groups. KTOT in {128, 256, 512}.
// ---------------------------------------------------------------------------
template<int ACT, int OUTM, int QSM, int KTOT>
__global__ __launch_bounds__(256) void gemm_als(
    const unsigned short* __restrict__ A, int lda,
    const unsigned short* __restrict__ Bt, int ldb,
    const float* __restrict__ bias,
    float* __restrict__ Cf, unsigned short* __restrict__ Cb,
    int ldc, long sA, long sB, long sC)
{
    constexpr int KB    = (KTOT >= 256) ? 256 : KTOT;   // K per LDS pass
    constexpr int NPASS = KTOT / KB;
    constexpr int CPR   = KB / 8;                        // 16B chunks per row
    constexpr int SSH   = (KB == 256) ? 5 : 4;
    constexpr int MSK   = CPR - 1;
    constexpr int RPC   = 512 / KB;                      // rows per GLDS16
    constexpr int NCALL = 32 / RPC;                      // calls per wave/pass

    A  += (size_t)blockIdx.z * sA;
    Bt += (size_t)blockIdx.z * sB;
    if (OUTM == 2) Cf += (size_t)blockIdx.z * sC;
    Cb += (size_t)blockIdx.z * sC;

    __shared__ __attribute__((aligned(16))) unsigned short As[128 * KB];

    const int t = threadIdx.x, lane = t & 63, wave = t >> 6;
    const int wm = wave & 1, wn = wave >> 1;
    const int m0b = blockIdx.x * 128;
    const int m0  = m0b + wm * 64;
    const int n0  = blockIdx.y * 128 + wn * 64;
    const int fm = lane & 15, fq = lane >> 4;

    const int srow   = lane >> SSH;       // staging row-offset within call
    const int schunk = lane & MSK;        // staging chunk

    const unsigned short* pbb = Bt + (size_t)(n0 + fm) * ldb + fq * 8;

    f32x4 acc[4][4];
    #pragma unroll
    for (int i = 0; i < 4; ++i)
        #pragma unroll
        for (int j = 0; j < 4; ++j) acc[i][j] = (f32x4)0.0f;

    #pragma unroll
    for (int p = 0; p < NPASS; ++p) {
        if (p) __syncthreads();
        const int kb0 = p * KB;
        #pragma unroll
        for (int i = 0; i < NCALL; ++i) {
            const int r  = wave * 32 + i * RPC + srow;
            const int gc = schunk ^ (r & 7);             // swizzled gather
            const unsigned short* g =
                A + (size_t)(m0b + r) * lda + kb0 + gc * 8;
            __builtin_amdgcn_global_load_lds(
                (gvoid*)g,
                (lvoid*)(As + (size_t)(wave * 32 + i * RPC) * KB + lane * 8),
                16, 0, 0);
        }
        __syncthreads();
        #pragma unroll
        for (int s = 0; s < KB / 32; ++s) {
            bf16x8 af[4], bg[4];
            #pragma unroll
            for (int i = 0; i < 4; ++i) {
                const int row = wm * 64 + i * 16 + fm;
                const int pch = (s * 4 + fq) ^ (row & 7);
                af[i] = *(const bf16x8*)(As + (size_t)row * KB + pch * 8);
            }
            #pragma unroll
            for (int j = 0; j < 4; ++j) {
                const uint4 r4 =
                    *(const uint4*)(pbb + (size_t)j * 16 * ldb + kb0 + s * 32);
                bg[j] = *(const bf16x8*)&r4;
            }
            #pragma unroll
            for (int i = 0; i < 4; ++i)
                #pragma unroll
                for (int j = 0; j < 4; ++j)
                    acc[i][j] = __builtin_amdgcn_mfma_f32_16x16x32_bf16(
                        bg[j], af[i], acc[i][j], 0, 0, 0);
        }
    }

    // epilogue (swapped layout): lane holds col m = i*16+fm, rows n = j*16+fq*4+r
    const int fq4 = fq * 4;
    #pragma unroll
    for (int i = 0; i < 4; ++i) {
        const int m = m0 + i * 16 + fm;
        float v[4][4];
        #pragma unroll
        for (int j = 0; j < 4; ++j) {
            const float4 b4 = *(const float4*)(bias + n0 + j * 16 + fq4);
            v[j][0] = acc[i][j][0] + b4.x;
            v[j][1] = acc[i][j][1] + b4.y;
            v[j][2] = acc[i][j][2] + b4.z;
            v[j][3] = acc[i][j][3] + b4.w;
            if (ACT == 1) {
                #pragma unroll
                for (int r = 0; r < 4; ++r) v[j][r] = fmaxf(v[j][r], 0.0f);
            }
            if (ACT == 2) {
                #pragma unroll
                for (int r = 0; r < 4; ++r)
                    v[j][r] = 0.5f * v[j][r] *
                              (1.0f + erff(v[j][r] * 0.7071067811865476f));
            }
        }
        if (QSM) {
            #pragma unroll
            for (int g = 0; g < 2; ++g) {
                float mx = -1e30f;
                #pragma unroll
                for (int j = 2 * g; j < 2 * g + 2; ++j)
                    #pragma unroll
                    for (int r = 0; r < 4; ++r) mx = fmaxf(mx, v[j][r]);
                mx = fmaxf(mx, __shfl_xor(mx, 16, 64));
                mx = fmaxf(mx, __shfl_xor(mx, 32, 64));
                float s = 0.0f;
                #pragma unroll
                for (int j = 2 * g; j < 2 * g + 2; ++j)
                    #pragma unroll
                    for (int r = 0; r < 4; ++r) {
                        v[j][r] = __expf(v[j][r] - mx);
                        s += v[j][r];
                    }
                s += __shfl_xor(s, 16, 64);
                s += __shfl_xor(s, 32, 64);
                const float rs = 1.0f / s;
                #pragma unroll
                for (int j = 2 * g; j < 2 * g + 2; ++j)
                    #pragma unroll
                    for (int r = 0; r < 4; ++r) v[j][r] *= rs;
            }
        }
        #pragma unroll
        for (int j = 0; j < 4; ++j) {
            const size_t off = (size_t)m * ldc + n0 + j * 16 + fq4;
            if (OUTM == 2) {
                float4 o4;
                o4.x = v[j][0]; o4.y = v[j][1]; o4.z = v[j][2]; o4.w = v[j][3];
                *(float4*)(Cf + off) = o4;
            }
            ushort4 u4;
            u4.x = f2bf(v[j][0]); u4.y = f2bf(v[j][1]);
            u4.z = f2bf(v[j][2]); u4.w = f2bf(v[j][3]);
            *(ushort4*)(Cb + off) = u4;
        }
    }
}

// ---------------------------------------------------------------------------
// one-shot weight conversion: transpose to [N][K] bf16 + bias concat
// ---------------------------------------------------------------------------
#define CW_QKV  786432   // 4*768*256
#define CW_O   1048576   // + 4*256*256
#define CW_1   1572864   // + 4*512*256
#define CW_2   2097152   // + 4*256*512
#define CW_X   2129920   // + 256*128
#define CW_B   2132992   // + 4*768
__global__ __launch_bounds__(256) void conv_weights(
    const float* __restrict__ Wq, const float* __restrict__ Wk,
    const float* __restrict__ Wv, const float* __restrict__ Wo,
    const float* __restrict__ fw1, const float* __restrict__ fw2,
    const float* __restrict__ Wx_w,
    const float* __restrict__ bq, const float* __restrict__ bk,
    const float* __restrict__ bv,
    unsigned short* __restrict__ wqkv_t, unsigned short* __restrict__ wo_t,
    unsigned short* __restrict__ w1_t, unsigned short* __restrict__ w2_t,
    unsigned short* __restrict__ wx_bf, float* __restrict__ bqkv)
{
    const int e = blockIdx.x * 256 + threadIdx.x;
    if (e < CW_QKV) {
        const int i = e / 196608, r = e % 196608;
        const int n = r / 256, k = r % 256;
        const float* src = (n < 256) ? Wq : (n < 512) ? Wk : Wv;
        wqkv_t[e] = f2bf(src[((size_t)i * 256 + k) * 256 + (n & 255)]);
    } else if (e < CW_O) {
        const int r = e - CW_QKV;
        const int i = r / 65536, rr = r % 65536, n = rr / 256, k = rr % 256;
        wo_t[r] = f2bf(Wo[((size_t)i * 256 + k) * 256 + n]);
    } else if (e < CW_1) {
        const int r = e - CW_O;
        const int i = r / 131072, rr = r % 131072, n = rr / 256, k = rr % 256;
        w1_t[r] = f2bf(fw1[((size_t)i * 256 + k) * 512 + n]);
    } else if (e < CW_2) {
        const int r = e - CW_1;
        const int i = r / 131072, rr = r % 131072, n = rr / 512, k = rr % 512;
        w2_t[r] = f2bf(fw2[((size_t)i * 512 + k) * 256 + n]);
    } else if (e < CW_X) {
        const int r = e - CW_2;
        wx_bf[r] = f2bf(Wx_w[r]);     // Wx_w [out][in] is already B^T layout
    } else if (e < CW_B) {
        const int r = e - CW_X;
        const int i = r / 768, j = r % 768;
        const float v = (j < 256) ? bq[i * 256 + j]
                      : (j < 512) ? bk[i * 256 + j - 256]
                                  : bv[i * 256 + j - 512];
        bqkv[r] = v;
    }
}

// ---------------------------------------------------------------------------
// x [B][CIN][NTOK] f32 -> xbf [(b,n)][CIN] bf16, LDS 32x32 tile transpose.
// ---------------------------------------------------------------------------
__global__ __launch_bounds__(256) void conv_x(
    const float* __restrict__ x, unsigned short* __restrict__ xbf)
{
    __shared__ float tile[32][33];
    const int n0 = blockIdx.x * 32;
    const int c0 = blockIdx.y * 32;
    const int b  = blockIdx.z;
    const int t = threadIdx.x;
    const int tn = t & 31, tc = t >> 5;
    #pragma unroll
    for (int p = 0; p < 4; ++p)
        tile[tc + p * 8][tn] =
            x[((size_t)(b * CIN + c0 + tc + p * 8)) * NTOK + n0 + tn];
    __syncthreads();
    const int cc = t & 31, nr = t >> 5;
    #pragma unroll
    for (int p = 0; p < 4; ++p)
        xbf[((size_t)(b * NTOK + n0 + nr + p * 8)) * CIN + c0 + cc] =
            f2bf(tile[cc][nr + p * 8]);
}

// ---------------------------------------------------------------------------
// kvt: qkv k,v slots -> expkT/vT [b][ch][tok] bf16 (exp applied to k).
// ---------------------------------------------------------------------------
__global__ __launch_bounds__(256) void kvt_kernel(
    const unsigned short* __restrict__ qkv, unsigned short* __restrict__ kvT)
{
    const int nb = blockIdx.x, h = blockIdx.y, b = blockIdx.z;
    const int n0 = nb * 64;
    const int t = threadIdx.x;
    __shared__ __attribute__((aligned(16))) unsigned short LT[64 * 72];
    const int tl = t >> 2, cg = t & 3;
    const unsigned short* src =
        qkv + ((size_t)(b * NTOK + n0 + tl)) * 768 + 256 + h * 32 + cg * 8;
    const uint4 kr = *(const uint4*)src;
    const uint4 vr = *(const uint4*)(src + 256);
    const unsigned short* ks = (const unsigned short*)&kr;
    const unsigned short* vs = (const unsigned short*)&vr;
    #pragma unroll
    for (int j = 0; j < 8; ++j) {
        const int ch = cg * 8 + j;
        LT[ch * 72 + tl]        = f2bf(__expf(bf2f(ks[j])));
        LT[(32 + ch) * 72 + tl] = vs[j];
    }
    __syncthreads();
    #pragma unroll
    for (int it = 0; it < 2; ++it) {
        const int idx = it * 256 + t;       // 0..511
        const int row = idx >> 3, seg = idx & 7;
        const uint4 val = *(const uint4*)(LT + row * 72 + seg * 8);
        const int ch = row & 31;
        const size_t dst = ((row >= 32) ? KVHALF : (size_t)0)
                         + ((size_t)(b * 256 + h * 32 + ch)) * NTOK + n0 + seg * 8;
        *(uint4*)(kvT + dst) = val;
    }
}

// ---------------------------------------------------------------------------
// ctx via MFMA, split-K, no atomics.
// ---------------------------------------------------------------------------
__global__ __launch_bounds__(256) void ctx_mfma(
    const unsigned short* __restrict__ kvT,
    float* __restrict__ ctxp, float* __restrict__ skp)
{
    const int s = blockIdx.x, h = blockIdx.y, b = blockIdx.z;
    const int t = threadIdx.x, w = t >> 6, l = t & 63;
    const int fm = l & 15, fq = (l >> 4) * 8;
    const size_t rowA = (size_t)(b * 256 + h * 32 + fm) * NTOK;
    const int n0 = s * 512 + w * 128 + fq;
    const unsigned short* pa = kvT + rowA + n0;
    const unsigned short* pb = kvT + KVHALF + rowA + n0;

    f32x4 acc[2][2];
    #pragma unroll
    for (int x = 0; x < 2; ++x)
        #pragma unroll
        for (int y = 0; y < 2; ++y) acc[x][y] = (f32x4)0.0f;
    float ss0 = 0.0f, ss1 = 0.0f;

    #pragma unroll
    for (int step = 0; step < 4; ++step) {
        const int ko = step * 32;
        const uint4 ra0 = *(const uint4*)(pa + ko);
        const uint4 ra1 = *(const uint4*)(pa + (size_t)16 * NTOK + ko);
        const uint4 rb0 = *(const uint4*)(pb + ko);
        const uint4 rb1 = *(const uint4*)(pb + (size_t)16 * NTOK + ko);
        const bf16x8 a0 = *(const bf16x8*)&ra0;
        const bf16x8 a1 = *(const bf16x8*)&ra1;
        const bf16x8 b0 = *(const bf16x8*)&rb0;
        const bf16x8 b1 = *(const bf16x8*)&rb1;
        acc[0][0] = __builtin_amdgcn_mfma_f32_16x16x32_bf16(a0, b0, acc[0][0], 0, 0, 0);
        acc[0][1] = __builtin_amdgcn_mfma_f32_16x16x32_bf16(a0, b1, acc[0][1], 0, 0, 0);
        acc[1][0] = __builtin_amdgcn_mfma_f32_16x16x32_bf16(a1, b0, acc[1][0], 0, 0, 0);
        acc[1][1] = __builtin_amdgcn_mfma_f32_16x16x32_bf16(a1, b1, acc[1][1], 0, 0, 0);
        const unsigned short* u0 = (const unsigned short*)&ra0;
        const unsigned short* u1 = (const unsigned short*)&ra1;
        #pragma unroll
        for (int j = 0; j < 8; ++j) { ss0 += bf2f(u0[j]); ss1 += bf2f(u1[j]); }
    }

    ss0 += __shfl_xor(ss0, 16, 64); ss0 += __shfl_xor(ss0, 32, 64);
    ss1 += __shfl_xor(ss1, 16, 64); ss1 += __shfl_xor(ss1, 32, 64);
    __shared__ float skw[4][32];
    __shared__ float redc[4][32][33];
    if (l < 16) { skw[w][fm] = ss0; skw[w][16 + fm] = ss1; }

    const int rb4 = (l >> 4) * 4;
    #pragma unroll
    for (int x = 0; x < 2; ++x)
        #pragma unroll
        for (int y = 0; y < 2; ++y)
            #pragma unroll
            for (int r = 0; r < 4; ++r)
                redc[w][x * 16 + rb4 + r][y * 16 + fm] = acc[x][y][r];
    __syncthreads();

    if (t < 32)
        skp[(size_t)s * 512 + b * 256 + h * 32 + t] =
            skw[0][t] + skw[1][t] + skw[2][t] + skw[3][t];

    const int e0 = t * 4;
    const int dd = e0 >> 5, c0 = e0 & 31;
    float4 o;
    o.x = redc[0][dd][c0+0] + redc[1][dd][c0+0] + redc[2][dd][c0+0] + redc[3][dd][c0+0];
    o.y = redc[0][dd][c0+1] + redc[1][dd][c0+1] + redc[2][dd][c0+1] + redc[3][dd][c0+1];
    o.z = redc[0][dd][c0+2] + redc[1][dd][c0+2] + redc[2][dd][c0+2] + redc[3][dd][c0+2];
    o.w = redc[0][dd][c0+3] + redc[1][dd][c0+3] + redc[2][dd][c0+3] + redc[3][dd][c0+3];
    *(float4*)(ctxp + ((size_t)s * 16 + b * 8 + h) * 1024 + e0) = o;
}

// reduce split-K partials: ctx[16][1024] and Sk[512]. grid 66 x 256.
__global__ __launch_bounds__(256) void ctxred(
    const float* __restrict__ ctxp, const float* __restrict__ skp,
    float* __restrict__ ctx, float* __restrict__ Sk)
{
    const int o = blockIdx.x * 256 + threadIdx.x;   // 0..16895
    if (o < 16384) {
        float a = 0.0f;
        for (int s = 0; s < NSPLIT; ++s) a += ctxp[(size_t)s * 16384 + o];
        ctx[o] = a;
    } else {
        const int c = o - 16384;
        float a = 0.0f;
        for (int s = 0; s < NSPLIT; ++s) a += skp[(size_t)s * 512 + c];
        Sk[c] = a;
    }
}

// ---------------------------------------------------------------------------
// W'[b][n][h*32+d] = (1/sqrt(dk)) * (1/Sk[d]) * sum_e ctx[b][h][d][e] * Wo[h*32+e][n]
// ---------------------------------------------------------------------------
__global__ __launch_bounds__(256) void ctxwo_kernel(
    const float* __restrict__ ctx, const float* __restrict__ Sk,
    const unsigned short* __restrict__ wo_t, unsigned short* __restrict__ wp)
{
    const int h = blockIdx.x, b = blockIdx.y;
    const int n = threadIdx.x;
    __shared__ float cl[1024];
    __shared__ float sdk[32];
    {
        const float* cp = ctx + (size_t)(b * 8 + h) * 1024;
        *(float4*)&cl[n * 4] = *(const float4*)&cp[n * 4];
    }
    if (n < 32) sdk[n] = 0.17677669529663687f / Sk[b * 256 + h * 32 + n];
    __syncthreads();
    float w[32];
    const unsigned short* wop = wo_t + (size_t)n * 256 + h * 32;
    #pragma unroll
    for (int e = 0; e < 32; ++e) w[e] = bf2f(wop[e]);
    unsigned short outv[32];
    #pragma unroll
    for (int d = 0; d < 32; ++d) {
        float acc = 0.0f;
        #pragma unroll
        for (int e = 0; e < 32; ++e) acc += cl[d * 32 + e] * w[e];
        outv[d] = f2bf(acc * sdk[d]);
    }
    unsigned short* op = wp + (size_t)b * 65536 + (size_t)n * 256 + h * 32;
    #pragma unroll
    for (int d = 0; d < 32; d += 8)
        *(uint4*)(op + d) = *(uint4*)(outv + d);
}

// ---------------------------------------------------------------------------
// t = LayerNorm(t + add(bf16)); writes t f32 in place (+ optional bf16 copy)
// ---------------------------------------------------------------------------
template<int WB>
__global__ __launch_bounds__(256) void ln_kernel(
    float* __restrict__ t, const unsigned short* __restrict__ add,
    const float* __restrict__ g, const float* __restrict__ bta,
    unsigned short* __restrict__ tbf)
{
    const int row = blockIdx.x;
    const int c = threadIdx.x;
    const int lane = c & 63, wave = c >> 6;
    const size_t off = (size_t)row * 256 + c;
    const float v = t[off] + bf2f(add[off]);
    __shared__ float red[8];
    float s = v;
    #pragma unroll
    for (int o = 32; o; o >>= 1) s += __shfl_xor(s, o, 64);
    if (lane == 0) red[wave] = s;
    __syncthreads();
    const float mu = (red[0] + red[1] + red[2] + red[3]) * (1.0f / 256.0f);
    const float dv = v - mu;
    float s2 = dv * dv;
    #pragma unroll
    for (int o = 32; o; o >>= 1) s2 += __shfl_xor(s2, o, 64);
    if (lane == 0) red[wave + 4] = s2;
    __syncthreads();
    const float var = (red[4] + red[5] + red[6] + red[7]) * (1.0f / 256.0f);
    const float o = dv * rsqrtf(var + 1e-6f) * g[c] + bta[c];
    t[off] = o;
    if (WB) tbf[off] = f2bf(o);
}

// ---------------------------------------------------------------------------
// depthwise 3x3x3 conv + residual, register-resident weights + sliding window.
// ---------------------------------------------------------------------------
template<int WB>
__global__ __launch_bounds__(256) void posconv_kernel(
    const float* __restrict__ tin, const float* __restrict__ pw,
    const float* __restrict__ pb, float* __restrict__ outp,
    unsigned short* __restrict__ tbfp)
{
    const int hw = blockIdx.x;            // 0..575
    const int b  = blockIdx.y;
    const int hh = hw / 24, ww = hw % 24;
    const int c  = threadIdx.x;

    float w[27];
    #pragma unroll
    for (int k = 0; k < 27; ++k) w[k] = pw[c * 27 + k];
    const float bias = pb[c];

    const float* base = tin + (size_t)b * NTOK * 256 + c;

    const float* colp[9];
    bool colok[9];
    #pragma unroll
    for (int dh = -1; dh <= 1; ++dh)
        #pragma unroll
        for (int dw = -1; dw <= 1; ++dw) {
            const int j = (dh + 1) * 3 + (dw + 1);
            const int h2 = hh + dh, w2 = ww + dw;
            colok[j] = ((unsigned)h2 < 24u) & ((unsigned)w2 < 24u);
            colp[j] = base + (size_t)((h2 * 24 + w2) * 24) * 256;
        }

    float win[9][3];
    #pragma unroll
    for (int j = 0; j < 9; ++j) {
        win[j][0] = 0.0f;
        win[j][1] = colok[j] ? colp[j][0] : 0.0f;
    }

    float* ob = outp + ((size_t)b * NTOK + (size_t)hw * 24) * 256 + c;
    unsigned short* tb = WB ? (tbfp + ((size_t)b * NTOK + (size_t)hw * 24) * 256 + c)
                            : (unsigned short*)nullptr;

    for (int d = 0; d < 24; ++d) {
        #pragma unroll
        for (int j = 0; j < 9; ++j)
            win[j][2] = (colok[j] && d < 23) ? colp[j][(d + 1) * 256] : 0.0f;

        float acc = bias + win[4][1];
        #pragma unroll
        for (int j = 0; j < 9; ++j) {
            acc += w[j * 3 + 0] * win[j][0];
            acc += w[j * 3 + 1] * win[j][1];
            acc += w[j * 3 + 2] * win[j][2];
        }
        ob[d * 256] = acc;
        if (WB) tb[d * 256] = f2bf(acc);

        #pragma unroll
        for (int j = 0; j < 9; ++j) { win[j][0] = win[j][1]; win[j][1] = win[j][2]; }
    }
}

// ---------------------------------------------------------------------------
// final transpose: t [MTOT][256] f32 -> out [B][256][NTOK] (LDS tiled)
// ---------------------------------------------------------------------------
__global__ __launch_bounds__(256) void tr_out(
    const float* __restrict__ tin, float* __restrict__ outp)
{
    __shared__ float tile[32][33];
    const int m0 = blockIdx.x * 32;
    const int c0 = blockIdx.y * 32;
    const int t = threadIdx.x;
    const int tc = t & 31, tr = t >> 5;
    #pragma unroll
    for (int r = 0; r < 4; ++r)
        tile[tr + r * 8][tc] = tin[(size_t)(m0 + tr + r * 8) * 256 + c0 + tc];
    __syncthreads();
    const int b = (m0 >= NTOK) ? 1 : 0;
    const int n0 = m0 - b * NTOK;
    #pragma unroll
    for (int r = 0; r < 4; ++r)
        outp[((size_t)b * 256 + c0 + tr + r * 8) * NTOK + n0 + tc] = tile[tc][tr + r * 8];
}

// ---------------------------------------------------------------------------
// launch
// ---------------------------------------------------------------------------
extern "C" void kernel_launch(void* const* d_in, const int* in_sizes, int n_in,
                              void* d_out, int out_size, void* d_ws, size_t ws_size,
                              hipStream_t stream)
{
    (void)in_sizes; (void)n_in; (void)out_size; (void)ws_size;
    const float* x     = (const float*)d_in[0];
    const float* Wx_w  = (const float*)d_in[1];
    const float* Wx_b  = (const float*)d_in[2];
    const float* Wq    = (const float*)d_in[3];
    const float* bq    = (const float*)d_in[4];
    const float* Wk    = (const float*)d_in[5];
    const float* bk    = (const float*)d_in[6];
    const float* Wv    = (const float*)d_in[7];
    const float* bv    = (const float*)d_in[8];
    const float* Wo    = (const float*)d_in[9];
    const float* bo    = (const float*)d_in[10];
    const float* ln1_g = (const float*)d_in[11];
    const float* ln1_b = (const float*)d_in[12];
    const float* ln2_g = (const float*)d_in[13];
    const float* ln2_b = (const float*)d_in[14];
    const float* fw1   = (const float*)d_in[15];
    const float* fb1   = (const float*)d_in[16];
    const float* fw2   = (const float*)d_in[17];
    const float* fb2   = (const float*)d_in[18];
    const float* pw    = (const float*)d_in[19];
    const float* pb    = (const float*)d_in[20];
    float* out = (float*)d_out;

    char* p = (char*)d_ws;
    float* tA            = (float*)p;          p += (size_t)MTOT * 256 * 4;
    float* tB            = (float*)p;          p += (size_t)MTOT * 256 * 4;
    unsigned short* tbf  = (unsigned short*)p; p += (size_t)MTOT * 256 * 2;
    unsigned short* qkv  = (unsigned short*)p; p += (size_t)MTOT * 768 * 2;
    unsigned short* hbf  = (unsigned short*)p; p += (size_t)MTOT * 512 * 2;   // also kvT
    unsigned short* ob   = (unsigned short*)p; p += (size_t)MTOT * 256 * 2;
    unsigned short* xbf  = (unsigned short*)p; p += (size_t)MTOT * 128 * 2;
    unsigned short* wqkv_t = (unsigned short*)p; p += (size_t)786432 * 2;
    unsigned short* wo_t   = (unsigned short*)p; p += (size_t)262144 * 2;
    unsigned short* w1_t   = (unsigned short*)p; p += (size_t)524288 * 2;
    unsigned short* w2_t   = (unsigned short*)p; p += (size_t)524288 * 2;
    unsigned short* wx_bf  = (unsigned short*)p; p += (size_t)32768 * 2;
    unsigned short* wp     = (unsigned short*)p; p += (size_t)BATCH * 65536 * 2;
    float* bqkv = (float*)p; p += 3072 * 4;
    float* ctx  = (float*)p; p += 16384 * 4;
    float* Sk   = (float*)p; p += 512 * 4;
    float* ctxp = (float*)p; p += (size_t)NSPLIT * 16384 * 4;
    float* skp  = (float*)p; p += (size_t)NSPLIT * 512 * 4;
    unsigned short* kvT = hbf;   // overlays FFN hidden (disjoint lifetime)

    hipLaunchKernelGGL(conv_weights, dim3(8333), dim3(256), 0, stream,
                       Wq, Wk, Wv, Wo, fw1, fw2, Wx_w, bq, bk, bv,
                       wqkv_t, wo_t, w1_t, w2_t, wx_bf, bqkv);
    hipLaunchKernelGGL(conv_x, dim3(NTOK / 32, CIN / 32, BATCH), dim3(256), 0, stream,
                       x, xbf);

    // input 1x1x1 conv + relu -> tA f32 + tbf bf16 (K=128)
    hipLaunchKernelGGL((gemm_als<1, 2, 0, 128>), dim3(216, 2, 1), dim3(256), 0, stream,
                       xbf, CIN, wx_bf, CIN, Wx_b, tA, tbf, 256,
                       (long)0, (long)0, (long)0);

    for (int i = 0; i < NLAYERS; ++i) {
        float* tin  = (i & 1) ? tB : tA;
        float* tout = (i & 1) ? tA : tB;

        // QKV q-part with fused q-softmax (cols 0..255)
        hipLaunchKernelGGL((gemm_als<0, 1, 1, 256>), dim3(216, 2, 1), dim3(256), 0, stream,
                           tbf, 256, wqkv_t + (size_t)i * 196608, 256,
                           bqkv + i * 768, nullptr, qkv, 768,
                           (long)0, (long)0, (long)0);
        // QKV k,v-part (cols 256..767)
        hipLaunchKernelGGL((gemm_als<0, 1, 0, 256>), dim3(216, 4, 1), dim3(256), 0, stream,
                           tbf, 256, wqkv_t + (size_t)i * 196608 + 65536, 256,
                           bqkv + i * 768 + 256, nullptr, qkv + 256, 768,
                           (long)0, (long)0, (long)0);

        // ctx path: transpose -> MFMA split-K -> reduce
        hipLaunchKernelGGL(kvt_kernel, dim3(NTOK / 64, NHEAD, BATCH), dim3(256), 0, stream,
                           qkv, kvT);
        hipLaunchKernelGGL(ctx_mfma, dim3(NSPLIT, NHEAD, BATCH), dim3(256), 0, stream,
                           kvT, ctxp, skp);
        hipLaunchKernelGGL(ctxred, dim3(66), dim3(256), 0, stream, ctxp, skp, ctx, Sk);

        // W' = (ctx/Sk) @ Wo (per batch)
        hipLaunchKernelGGL(ctxwo_kernel, dim3(NHEAD, BATCH), dim3(256), 0, stream,
                           ctx, Sk, wo_t + (size_t)i * 65536, wp);

        // o_proj = qs @ W' + bo  (batched over z)
        hipLaunchKernelGGL((gemm_als<0, 1, 0, 256>), dim3(108, 2, BATCH), dim3(256), 0, stream,
                           qkv, 768, wp, 256, bo + i * 256, nullptr, ob, 256,
                           (long)NTOK * 768, (long)65536, (long)NTOK * 256);

        hipLaunchKernelGGL((ln_kernel<1>), dim3(MTOT), dim3(256), 0, stream,
                           tin, ob, ln1_g + i * 256, ln1_b + i * 256, tbf);

        // FFN (hbf free again: kvT consumed)
        hipLaunchKernelGGL((gemm_als<2, 1, 0, 256>), dim3(216, 4, 1), dim3(256), 0, stream,
                           tbf, 256, w1_t + (size_t)i * 131072, 256,
                           fb1 + i * 512, nullptr, hbf, 512,
                           (long)0, (long)0, (long)0);
        hipLaunchKernelGGL((gemm_als<0, 1, 0, 512>), dim3(216, 2, 1), dim3(256), 0, stream,
                           hbf, 512, w2_t + (size_t)i * 131072, 512,
                           fb2 + i * 256, nullptr, ob, 256,
                           (long)0, (long)0, (long)0);
        hipLaunchKernelGGL((ln_kernel<0>), dim3(MTOT), dim3(256), 0, stream,
                           tin, ob, ln2_g + i * 256, ln2_b + i * 256, nullptr);

        // depthwise conv + residual -> tout f32 (+ tbf bf16 except last layer)
        if (i < NLAYERS - 1)
            hipLaunchKernelGGL((posconv_kernel<1>), dim3(576, BATCH), dim3(256), 0, stream,
                               tin, pw + (size_t)i * 6912, pb + i * 256, tout, tbf);
        else
            hipLaunchKernelGGL((posconv_kernel<0>), dim3(576, BATCH), dim3(256), 0, stream,
                               tin, pw + (size_t)i * 6912, pb + i * 256, tout, nullptr);
    }

    // layer 3 wrote tA
    hipLaunchKernelGGL(tr_out, dim3(MTOT / 32, 8), dim3(256), 0, stream, tA, out);
}

// Round 10
// 942.731 us; speedup vs baseline: 1.4213x; 1.0927x over previous
//
#include <hip/hip_runtime.h>
#include <math.h>

#define NTOK 13824            // 24*24*24
#define MTOT 27648            // B*NTOK
#define BATCH 2
#define CIN 128
#define DMODEL 256
#define NHEAD 8
#define NLAYERS 4
#define DFF 512
#define NSPLIT 27
#define KVHALF ((size_t)BATCH * 256 * NTOK)

typedef float f32x4 __attribute__((ext_vector_type(4)));
typedef __bf16 bf16x8 __attribute__((ext_vector_type(8)));
typedef __attribute__((address_space(1))) void gvoid;
typedef __attribute__((address_space(3))) void lvoid;

__device__ __forceinline__ unsigned short f2bf(float f) {
    unsigned u = __float_as_uint(f);
    return (unsigned short)((u + 0x7FFFu + ((u >> 16) & 1u)) >> 16);
}
__device__ __forceinline__ float bf2f(unsigned short h) {
    return __uint_as_float(((unsigned)h) << 16);
}

// ---------------------------------------------------------------------------
// v3 bf16 MFMA GEMM for tall-skinny shapes (M huge, K in {128,256,512}).
// 64x128 block tile, A staged in LDS for a full 256-K pass (32 KB ->
// ~5 blocks/CU co-resident), ONE barrier per pass, K-loop barrier-free:
// A from swizzled LDS (ds_read_b128, 2-way), B direct from global (weight
// tile, L2-hot). 4 waves; wave w owns N-strip [w*32, w*32+32).
// Swapped mfma(bg, af): lane (fm,fq) holds D[m=i*16+fm][n=j*16+fq*4+r]
// -> packed 8B stores. QSM: fused q-softmax over the wave's 32-n head group,
// applied only when block's n-base < 256 (q columns of fused QKV).
// ---------------------------------------------------------------------------
template<int ACT, int OUTM, int QSM, int KTOT>
__global__ __launch_bounds__(256) void gemm_v3(
    const unsigned short* __restrict__ A, int lda,
    const unsigned short* __restrict__ Bt, int ldb,
    const float* __restrict__ bias,
    float* __restrict__ Cf, unsigned short* __restrict__ Cb,
    int ldc, long sA, long sB, long sC)
{
    constexpr int KB    = (KTOT >= 256) ? 256 : KTOT;   // K per LDS pass
    constexpr int NPASS = KTOT / KB;
    constexpr int CPR   = KB / 8;        // 16B chunks per row
    constexpr int RPC   = 512 / KB;      // rows per GLDS16 call (1KB/wave)
    constexpr int NCALL = 16 / RPC;      // calls per wave per pass

    A  += (size_t)blockIdx.z * sA;
    Bt += (size_t)blockIdx.z * sB;
    if (OUTM == 2) Cf += (size_t)blockIdx.z * sC;
    Cb += (size_t)blockIdx.z * sC;

    __shared__ __attribute__((aligned(16))) unsigned short As[64 * KB];

    const int t = threadIdx.x, lane = t & 63, w = t >> 6;
    const int m0b = blockIdx.x * 64;
    const int n0b = blockIdx.y * 128;
    const int n0w = n0b + w * 32;
    const int fm = lane & 15, fq = lane >> 4;

    const int srow = lane / CPR;          // row offset within staging call
    const int sch  = lane % CPR;          // chunk within row

    const unsigned short* pb0 = Bt + (size_t)(n0w + fm) * ldb + fq * 8;
    const unsigned short* pb1 = Bt + (size_t)(n0w + 16 + fm) * ldb + fq * 8;

    f32x4 acc[4][2];
    #pragma unroll
    for (int i = 0; i < 4; ++i) {
        acc[i][0] = (f32x4)0.0f;
        acc[i][1] = (f32x4)0.0f;
    }

    #pragma unroll
    for (int p = 0; p < NPASS; ++p) {
        if (p) __syncthreads();
        const int kb0 = p * KB;
        #pragma unroll
        for (int c = 0; c < NCALL; ++c) {
            const int r  = w * 16 + c * RPC + srow;
            const int gc = sch ^ (r & 7);             // swizzled gather
            __builtin_amdgcn_global_load_lds(
                (gvoid*)(A + (size_t)(m0b + r) * lda + kb0 + gc * 8),
                (lvoid*)(As + (size_t)(w * 16 + c * RPC) * KB + lane * 8),
                16, 0, 0);
        }
        __syncthreads();
        #pragma unroll
        for (int s = 0; s < KB / 32; ++s) {
            bf16x8 af[4], bg[2];
            #pragma unroll
            for (int i = 0; i < 4; ++i) {
                const int row = i * 16 + fm;
                const int pch = (s * 4 + fq) ^ (row & 7);
                af[i] = *(const bf16x8*)(As + (size_t)row * KB + pch * 8);
            }
            {
                const uint4 r0 = *(const uint4*)(pb0 + kb0 + s * 32);
                const uint4 r1 = *(const uint4*)(pb1 + kb0 + s * 32);
                bg[0] = *(const bf16x8*)&r0;
                bg[1] = *(const bf16x8*)&r1;
            }
            #pragma unroll
            for (int i = 0; i < 4; ++i) {
                acc[i][0] = __builtin_amdgcn_mfma_f32_16x16x32_bf16(
                    bg[0], af[i], acc[i][0], 0, 0, 0);
                acc[i][1] = __builtin_amdgcn_mfma_f32_16x16x32_bf16(
                    bg[1], af[i], acc[i][1], 0, 0, 0);
            }
        }
    }

    // epilogue: lane (fm,fq) holds D[m=i*16+fm][n=n0w+j*16+fq*4+r]
    const int fq4 = fq * 4;
    const bool doq = QSM && (n0b < 256);
    #pragma unroll
    for (int i = 0; i < 4; ++i) {
        const int m = m0b + i * 16 + fm;
        float v[2][4];
        #pragma unroll
        for (int j = 0; j < 2; ++j) {
            const float4 b4 = *(const float4*)(bias + n0w + j * 16 + fq4);
            v[j][0] = acc[i][j][0] + b4.x;
            v[j][1] = acc[i][j][1] + b4.y;
            v[j][2] = acc[i][j][2] + b4.z;
            v[j][3] = acc[i][j][3] + b4.w;
            if (ACT == 1) {
                #pragma unroll
                for (int r = 0; r < 4; ++r) v[j][r] = fmaxf(v[j][r], 0.0f);
            }
            if (ACT == 2) {
                #pragma unroll
                for (int r = 0; r < 4; ++r)
                    v[j][r] = 0.5f * v[j][r] *
                              (1.0f + erff(v[j][r] * 0.7071067811865476f));
            }
        }
        if (doq) {
            float mx = -1e30f;
            #pragma unroll
            for (int j = 0; j < 2; ++j)
                #pragma unroll
                for (int r = 0; r < 4; ++r) mx = fmaxf(mx, v[j][r]);
            mx = fmaxf(mx, __shfl_xor(mx, 16, 64));
            mx = fmaxf(mx, __shfl_xor(mx, 32, 64));
            float s = 0.0f;
            #pragma unroll
            for (int j = 0; j < 2; ++j)
                #pragma unroll
                for (int r = 0; r < 4; ++r) {
                    v[j][r] = __expf(v[j][r] - mx);
                    s += v[j][r];
                }
            s += __shfl_xor(s, 16, 64);
            s += __shfl_xor(s, 32, 64);
            const float rs = 1.0f / s;
            #pragma unroll
            for (int j = 0; j < 2; ++j)
                #pragma unroll
                for (int r = 0; r < 4; ++r) v[j][r] *= rs;
        }
        #pragma unroll
        for (int j = 0; j < 2; ++j) {
            const size_t off = (size_t)m * ldc + n0w + j * 16 + fq4;
            if (OUTM == 2) {
                float4 o4;
                o4.x = v[j][0]; o4.y = v[j][1]; o4.z = v[j][2]; o4.w = v[j][3];
                *(float4*)(Cf + off) = o4;
            }
            ushort4 u4;
            u4.x = f2bf(v[j][0]); u4.y = f2bf(v[j][1]);
            u4.z = f2bf(v[j][2]); u4.w = f2bf(v[j][3]);
            *(ushort4*)(Cb + off) = u4;
        }
    }
}

// ---------------------------------------------------------------------------
// one-shot weight conversion: transpose to [N][K] bf16 + bias concat
// ---------------------------------------------------------------------------
#define CW_QKV  786432   // 4*768*256
#define CW_O   1048576   // + 4*256*256
#define CW_1   1572864   // + 4*512*256
#define CW_2   2097152   // + 4*256*512
#define CW_X   2129920   // + 256*128
#define CW_B   2132992   // + 4*768
__global__ __launch_bounds__(256) void conv_weights(
    const float* __restrict__ Wq, const float* __restrict__ Wk,
    const float* __restrict__ Wv, const float* __restrict__ Wo,
    const float* __restrict__ fw1, const float* __restrict__ fw2,
    const float* __restrict__ Wx_w,
    const float* __restrict__ bq, const float* __restrict__ bk,
    const float* __restrict__ bv,
    unsigned short* __restrict__ wqkv_t, unsigned short* __restrict__ wo_t,
    unsigned short* __restrict__ w1_t, unsigned short* __restrict__ w2_t,
    unsigned short* __restrict__ wx_bf, float* __restrict__ bqkv)
{
    const int e = blockIdx.x * 256 + threadIdx.x;
    if (e < CW_QKV) {
        const int i = e / 196608, r = e % 196608;
        const int n = r / 256, k = r % 256;
        const float* src = (n < 256) ? Wq : (n < 512) ? Wk : Wv;
        wqkv_t[e] = f2bf(src[((size_t)i * 256 + k) * 256 + (n & 255)]);
    } else if (e < CW_O) {
        const int r = e - CW_QKV;
        const int i = r / 65536, rr = r % 65536, n = rr / 256, k = rr % 256;
        wo_t[r] = f2bf(Wo[((size_t)i * 256 + k) * 256 + n]);
    } else if (e < CW_1) {
        const int r = e - CW_O;
        const int i = r / 131072, rr = r % 131072, n = rr / 256, k = rr % 256;
        w1_t[r] = f2bf(fw1[((size_t)i * 256 + k) * 512 + n]);
    } else if (e < CW_2) {
        const int r = e - CW_1;
        const int i = r / 131072, rr = r % 131072, n = rr / 512, k = rr % 512;
        w2_t[r] = f2bf(fw2[((size_t)i * 512 + k) * 256 + n]);
    } else if (e < CW_X) {
        const int r = e - CW_2;
        wx_bf[r] = f2bf(Wx_w[r]);     // Wx_w [out][in] is already B^T layout
    } else if (e < CW_B) {
        const int r = e - CW_X;
        const int i = r / 768, j = r % 768;
        const float v = (j < 256) ? bq[i * 256 + j]
                      : (j < 512) ? bk[i * 256 + j - 256]
                                  : bv[i * 256 + j - 512];
        bqkv[r] = v;
    }
}

// ---------------------------------------------------------------------------
// x [B][CIN][NTOK] f32 -> xbf [(b,n)][CIN] bf16, LDS 32x32 tile transpose.
// ---------------------------------------------------------------------------
__global__ __launch_bounds__(256) void conv_x(
    const float* __restrict__ x, unsigned short* __restrict__ xbf)
{
    __shared__ float tile[32][33];
    const int n0 = blockIdx.x * 32;
    const int c0 = blockIdx.y * 32;
    const int b  = blockIdx.z;
    const int t = threadIdx.x;
    const int tn = t & 31, tc = t >> 5;
    #pragma unroll
    for (int p = 0; p < 4; ++p)
        tile[tc + p * 8][tn] =
            x[((size_t)(b * CIN + c0 + tc + p * 8)) * NTOK + n0 + tn];
    __syncthreads();
    const int cc = t & 31, nr = t >> 5;
    #pragma unroll
    for (int p = 0; p < 4; ++p)
        xbf[((size_t)(b * NTOK + n0 + nr + p * 8)) * CIN + c0 + cc] =
            f2bf(tile[cc][nr + p * 8]);
}

// ---------------------------------------------------------------------------
// kvt: qkv k,v slots -> expkT/vT [b][ch][tok] bf16 (exp applied to k).
// ---------------------------------------------------------------------------
__global__ __launch_bounds__(256) void kvt_kernel(
    const unsigned short* __restrict__ qkv, unsigned short* __restrict__ kvT)
{
    const int nb = blockIdx.x, h = blockIdx.y, b = blockIdx.z;
    const int n0 = nb * 64;
    const int t = threadIdx.x;
    __shared__ __attribute__((aligned(16))) unsigned short LT[64 * 72];
    const int tl = t >> 2, cg = t & 3;
    const unsigned short* src =
        qkv + ((size_t)(b * NTOK + n0 + tl)) * 768 + 256 + h * 32 + cg * 8;
    const uint4 kr = *(const uint4*)src;
    const uint4 vr = *(const uint4*)(src + 256);
    const unsigned short* ks = (const unsigned short*)&kr;
    const unsigned short* vs = (const unsigned short*)&vr;
    #pragma unroll
    for (int j = 0; j < 8; ++j) {
        const int ch = cg * 8 + j;
        LT[ch * 72 + tl]        = f2bf(__expf(bf2f(ks[j])));
        LT[(32 + ch) * 72 + tl] = vs[j];
    }
    __syncthreads();
    #pragma unroll
    for (int it = 0; it < 2; ++it) {
        const int idx = it * 256 + t;       // 0..511
        const int row = idx >> 3, seg = idx & 7;
        const uint4 val = *(const uint4*)(LT + row * 72 + seg * 8);
        const int ch = row & 31;
        const size_t dst = ((row >= 32) ? KVHALF : (size_t)0)
                         + ((size_t)(b * 256 + h * 32 + ch)) * NTOK + n0 + seg * 8;
        *(uint4*)(kvT + dst) = val;
    }
}

// ---------------------------------------------------------------------------
// ctx via MFMA, split-K, no atomics.
// ---------------------------------------------------------------------------
__global__ __launch_bounds__(256) void ctx_mfma(
    const unsigned short* __restrict__ kvT,
    float* __restrict__ ctxp, float* __restrict__ skp)
{
    const int s = blockIdx.x, h = blockIdx.y, b = blockIdx.z;
    const int t = threadIdx.x, w = t >> 6, l = t & 63;
    const int fm = l & 15, fq = (l >> 4) * 8;
    const size_t rowA = (size_t)(b * 256 + h * 32 + fm) * NTOK;
    const int n0 = s * 512 + w * 128 + fq;
    const unsigned short* pa = kvT + rowA + n0;
    const unsigned short* pb = kvT + KVHALF + rowA + n0;

    f32x4 acc[2][2];
    #pragma unroll
    for (int x = 0; x < 2; ++x)
        #pragma unroll
        for (int y = 0; y < 2; ++y) acc[x][y] = (f32x4)0.0f;
    float ss0 = 0.0f, ss1 = 0.0f;

    #pragma unroll
    for (int step = 0; step < 4; ++step) {
        const int ko = step * 32;
        const uint4 ra0 = *(const uint4*)(pa + ko);
        const uint4 ra1 = *(const uint4*)(pa + (size_t)16 * NTOK + ko);
        const uint4 rb0 = *(const uint4*)(pb + ko);
        const uint4 rb1 = *(const uint4*)(pb + (size_t)16 * NTOK + ko);
        const bf16x8 a0 = *(const bf16x8*)&ra0;
        const bf16x8 a1 = *(const bf16x8*)&ra1;
        const bf16x8 b0 = *(const bf16x8*)&rb0;
        const bf16x8 b1 = *(const bf16x8*)&rb1;
        acc[0][0] = __builtin_amdgcn_mfma_f32_16x16x32_bf16(a0, b0, acc[0][0], 0, 0, 0);
        acc[0][1] = __builtin_amdgcn_mfma_f32_16x16x32_bf16(a0, b1, acc[0][1], 0, 0, 0);
        acc[1][0] = __builtin_amdgcn_mfma_f32_16x16x32_bf16(a1, b0, acc[1][0], 0, 0, 0);
        acc[1][1] = __builtin_amdgcn_mfma_f32_16x16x32_bf16(a1, b1, acc[1][1], 0, 0, 0);
        const unsigned short* u0 = (const unsigned short*)&ra0;
        const unsigned short* u1 = (const unsigned short*)&ra1;
        #pragma unroll
        for (int j = 0; j < 8; ++j) { ss0 += bf2f(u0[j]); ss1 += bf2f(u1[j]); }
    }

    ss0 += __shfl_xor(ss0, 16, 64); ss0 += __shfl_xor(ss0, 32, 64);
    ss1 += __shfl_xor(ss1, 16, 64); ss1 += __shfl_xor(ss1, 32, 64);
    __shared__ float skw[4][32];
    __shared__ float redc[4][32][33];
    if (l < 16) { skw[w][fm] = ss0; skw[w][16 + fm] = ss1; }

    const int rb4 = (l >> 4) * 4;
    #pragma unroll
    for (int x = 0; x < 2; ++x)
        #pragma unroll
        for (int y = 0; y < 2; ++y)
            #pragma unroll
            for (int r = 0; r < 4; ++r)
                redc[w][x * 16 + rb4 + r][y * 16 + fm] = acc[x][y][r];
    __syncthreads();

    if (t < 32)
        skp[(size_t)s * 512 + b * 256 + h * 32 + t] =
            skw[0][t] + skw[1][t] + skw[2][t] + skw[3][t];

    const int e0 = t * 4;
    const int dd = e0 >> 5, c0 = e0 & 31;
    float4 o;
    o.x = redc[0][dd][c0+0] + redc[1][dd][c0+0] + redc[2][dd][c0+0] + redc[3][dd][c0+0];
    o.y = redc[0][dd][c0+1] + redc[1][dd][c0+1] + redc[2][dd][c0+1] + redc[3][dd][c0+1];
    o.z = redc[0][dd][c0+2] + redc[1][dd][c0+2] + redc[2][dd][c0+2] + redc[3][dd][c0+2];
    o.w = redc[0][dd][c0+3] + redc[1][dd][c0+3] + redc[2][dd][c0+3] + redc[3][dd][c0+3];
    *(float4*)(ctxp + ((size_t)s * 16 + b * 8 + h) * 1024 + e0) = o;
}

// reduce split-K partials: ctx[16][1024] and Sk[512]. grid 66 x 256.
__global__ __launch_bounds__(256) void ctxred(
    const float* __restrict__ ctxp, const float* __restrict__ skp,
    float* __restrict__ ctx, float* __restrict__ Sk)
{
    const int o = blockIdx.x * 256 + threadIdx.x;   // 0..16895
    if (o < 16384) {
        float a = 0.0f;
        for (int s = 0; s < NSPLIT; ++s) a += ctxp[(size_t)s * 16384 + o];
        ctx[o] = a;
    } else {
        const int c = o - 16384;
        float a = 0.0f;
        for (int s = 0; s < NSPLIT; ++s) a += skp[(size_t)s * 512 + c];
        Sk[c] = a;
    }
}

// ---------------------------------------------------------------------------
// W'[b][n][h*32+d] = (1/sqrt(dk)) * (1/Sk[d]) * sum_e ctx[b][h][d][e] * Wo[h*32+e][n]
// ---------------------------------------------------------------------------
__global__ __launch_bounds__(256) void ctxwo_kernel(
    const float* __restrict__ ctx, const float* __restrict__ Sk,
    const unsigned short* __restrict__ wo_t, unsigned short* __restrict__ wp)
{
    const int h = blockIdx.x, b = blockIdx.y;
    const int n = threadIdx.x;
    __shared__ float cl[1024];
    __shared__ float sdk[32];
    {
        const float* cp = ctx + (size_t)(b * 8 + h) * 1024;
        *(float4*)&cl[n * 4] = *(const float4*)&cp[n * 4];
    }
    if (n < 32) sdk[n] = 0.17677669529663687f / Sk[b * 256 + h * 32 + n];
    __syncthreads();
    float w[32];
    const unsigned short* wop = wo_t + (size_t)n * 256 + h * 32;
    #pragma unroll
    for (int e = 0; e < 32; ++e) w[e] = bf2f(wop[e]);
    unsigned short outv[32];
    #pragma unroll
    for (int d = 0; d < 32; ++d) {
        float acc = 0.0f;
        #pragma unroll
        for (int e = 0; e < 32; ++e) acc += cl[d * 32 + e] * w[e];
        outv[d] = f2bf(acc * sdk[d]);
    }
    unsigned short* op = wp + (size_t)b * 65536 + (size_t)n * 256 + h * 32;
    #pragma unroll
    for (int d = 0; d < 32; d += 8)
        *(uint4*)(op + d) = *(uint4*)(outv + d);
}

// ---------------------------------------------------------------------------
// t = LayerNorm(t + add(bf16)); writes t f32 in place (+ optional bf16 copy)
// ---------------------------------------------------------------------------
template<int WB>
__global__ __launch_bounds__(256) void ln_kernel(
    float* __restrict__ t, const unsigned short* __restrict__ add,
    const float* __restrict__ g, const float* __restrict__ bta,
    unsigned short* __restrict__ tbf)
{
    const int row = blockIdx.x;
    const int c = threadIdx.x;
    const int lane = c & 63, wave = c >> 6;
    const size_t off = (size_t)row * 256 + c;
    const float v = t[off] + bf2f(add[off]);
    __shared__ float red[8];
    float s = v;
    #pragma unroll
    for (int o = 32; o; o >>= 1) s += __shfl_xor(s, o, 64);
    if (lane == 0) red[wave] = s;
    __syncthreads();
    const float mu = (red[0] + red[1] + red[2] + red[3]) * (1.0f / 256.0f);
    const float dv = v - mu;
    float s2 = dv * dv;
    #pragma unroll
    for (int o = 32; o; o >>= 1) s2 += __shfl_xor(s2, o, 64);
    if (lane == 0) red[wave + 4] = s2;
    __syncthreads();
    const float var = (red[4] + red[5] + red[6] + red[7]) * (1.0f / 256.0f);
    const float o = dv * rsqrtf(var + 1e-6f) * g[c] + bta[c];
    t[off] = o;
    if (WB) tbf[off] = f2bf(o);
}

// ---------------------------------------------------------------------------
// depthwise 3x3x3 conv + residual, register-resident weights + sliding window.
// ---------------------------------------------------------------------------
template<int WB>
__global__ __launch_bounds__(256) void posconv_kernel(
    const float* __restrict__ tin, const float* __restrict__ pw,
    const float* __restrict__ pb, float* __restrict__ outp,
    unsigned short* __restrict__ tbfp)
{
    const int hw = blockIdx.x;            // 0..575
    const int b  = blockIdx.y;
    const int hh = hw / 24, ww = hw % 24;
    const int c  = threadIdx.x;

    float w[27];
    #pragma unroll
    for (int k = 0; k < 27; ++k) w[k] = pw[c * 27 + k];
    const float bias = pb[c];

    const float* base = tin + (size_t)b * NTOK * 256 + c;

    const float* colp[9];
    bool colok[9];
    #pragma unroll
    for (int dh = -1; dh <= 1; ++dh)
        #pragma unroll
        for (int dw = -1; dw <= 1; ++dw) {
            const int j = (dh + 1) * 3 + (dw + 1);
            const int h2 = hh + dh, w2 = ww + dw;
            colok[j] = ((unsigned)h2 < 24u) & ((unsigned)w2 < 24u);
            colp[j] = base + (size_t)((h2 * 24 + w2) * 24) * 256;
        }

    float win[9][3];
    #pragma unroll
    for (int j = 0; j < 9; ++j) {
        win[j][0] = 0.0f;
        win[j][1] = colok[j] ? colp[j][0] : 0.0f;
    }

    float* ob = outp + ((size_t)b * NTOK + (size_t)hw * 24) * 256 + c;
    unsigned short* tb = WB ? (tbfp + ((size_t)b * NTOK + (size_t)hw * 24) * 256 + c)
                            : (unsigned short*)nullptr;

    for (int d = 0; d < 24; ++d) {
        #pragma unroll
        for (int j = 0; j < 9; ++j)
            win[j][2] = (colok[j] && d < 23) ? colp[j][(d + 1) * 256] : 0.0f;

        float acc = bias + win[4][1];
        #pragma unroll
        for (int j = 0; j < 9; ++j) {
            acc += w[j * 3 + 0] * win[j][0];
            acc += w[j * 3 + 1] * win[j][1];
            acc += w[j * 3 + 2] * win[j][2];
        }
        ob[d * 256] = acc;
        if (WB) tb[d * 256] = f2bf(acc);

        #pragma unroll
        for (int j = 0; j < 9; ++j) { win[j][0] = win[j][1]; win[j][1] = win[j][2]; }
    }
}

// ---------------------------------------------------------------------------
// final transpose: t [MTOT][256] f32 -> out [B][256][NTOK] (LDS tiled)
// ---------------------------------------------------------------------------
__global__ __launch_bounds__(256) void tr_out(
    const float* __restrict__ tin, float* __restrict__ outp)
{
    __shared__ float tile[32][33];
    const int m0 = blockIdx.x * 32;
    const int c0 = blockIdx.y * 32;
    const int t = threadIdx.x;
    const int tc = t & 31, tr = t >> 5;
    #pragma unroll
    for (int r = 0; r < 4; ++r)
        tile[tr + r * 8][tc] = tin[(size_t)(m0 + tr + r * 8) * 256 + c0 + tc];
    __syncthreads();
    const int b = (m0 >= NTOK) ? 1 : 0;
    const int n0 = m0 - b * NTOK;
    #pragma unroll
    for (int r = 0; r < 4; ++r)
        outp[((size_t)b * 256 + c0 + tr + r * 8) * NTOK + n0 + tc] = tile[tc][tr + r * 8];
}

// ---------------------------------------------------------------------------
// launch
// ---------------------------------------------------------------------------
extern "C" void kernel_launch(void* const* d_in, const int* in_sizes, int n_in,
                              void* d_out, int out_size, void* d_ws, size_t ws_size,
                              hipStream_t stream)
{
    (void)in_sizes; (void)n_in; (void)out_size; (void)ws_size;
    const float* x     = (const float*)d_in[0];
    const float* Wx_w  = (const float*)d_in[1];
    const float* Wx_b  = (const float*)d_in[2];
    const float* Wq    = (const float*)d_in[3];
    const float* bq    = (const float*)d_in[4];
    const float* Wk    = (const float*)d_in[5];
    const float* bk    = (const float*)d_in[6];
    const float* Wv    = (const float*)d_in[7];
    const float* bv    = (const float*)d_in[8];
    const float* Wo    = (const float*)d_in[9];
    const float* bo    = (const float*)d_in[10];
    const float* ln1_g = (const float*)d_in[11];
    const float* ln1_b = (const float*)d_in[12];
    const float* ln2_g = (const float*)d_in[13];
    const float* ln2_b = (const float*)d_in[14];
    const float* fw1   = (const float*)d_in[15];
    const float* fb1   = (const float*)d_in[16];
    const float* fw2   = (const float*)d_in[17];
    const float* fb2   = (const float*)d_in[18];
    const float* pw    = (const float*)d_in[19];
    const float* pb    = (const float*)d_in[20];
    float* out = (float*)d_out;

    char* p = (char*)d_ws;
    float* tA            = (float*)p;          p += (size_t)MTOT * 256 * 4;
    float* tB            = (float*)p;          p += (size_t)MTOT * 256 * 4;
    unsigned short* tbf  = (unsigned short*)p; p += (size_t)MTOT * 256 * 2;
    unsigned short* qkv  = (unsigned short*)p; p += (size_t)MTOT * 768 * 2;
    unsigned short* hbf  = (unsigned short*)p; p += (size_t)MTOT * 512 * 2;   // also kvT
    unsigned short* ob   = (unsigned short*)p; p += (size_t)MTOT * 256 * 2;
    unsigned short* xbf  = (unsigned short*)p; p += (size_t)MTOT * 128 * 2;
    unsigned short* wqkv_t = (unsigned short*)p; p += (size_t)786432 * 2;
    unsigned short* wo_t   = (unsigned short*)p; p += (size_t)262144 * 2;
    unsigned short* w1_t   = (unsigned short*)p; p += (size_t)524288 * 2;
    unsigned short* w2_t   = (unsigned short*)p; p += (size_t)524288 * 2;
    unsigned short* wx_bf  = (unsigned short*)p; p += (size_t)32768 * 2;
    unsigned short* wp     = (unsigned short*)p; p += (size_t)BATCH * 65536 * 2;
    float* bqkv = (float*)p; p += 3072 * 4;
    float* ctx  = (float*)p; p += 16384 * 4;
    float* Sk   = (float*)p; p += 512 * 4;
    float* ctxp = (float*)p; p += (size_t)NSPLIT * 16384 * 4;
    float* skp  = (float*)p; p += (size_t)NSPLIT * 512 * 4;
    unsigned short* kvT = hbf;   // overlays FFN hidden (disjoint lifetime)

    hipLaunchKernelGGL(conv_weights, dim3(8333), dim3(256), 0, stream,
                       Wq, Wk, Wv, Wo, fw1, fw2, Wx_w, bq, bk, bv,
                       wqkv_t, wo_t, w1_t, w2_t, wx_bf, bqkv);
    hipLaunchKernelGGL(conv_x, dim3(NTOK / 32, CIN / 32, BATCH), dim3(256), 0, stream,
                       x, xbf);

    // input 1x1x1 conv + relu -> tA f32 + tbf bf16 (K=128)
    hipLaunchKernelGGL((gemm_v3<1, 2, 0, 128>), dim3(432, 2, 1), dim3(256), 0, stream,
                       xbf, CIN, wx_bf, CIN, Wx_b, tA, tbf, 256,
                       (long)0, (long)0, (long)0);

    for (int i = 0; i < NLAYERS; ++i) {
        float* tin  = (i & 1) ? tB : tA;
        float* tout = (i & 1) ? tA : tB;

        // fused QKV (N=768) with q-softmax on the q columns (y<2)
        hipLaunchKernelGGL((gemm_v3<0, 1, 1, 256>), dim3(432, 6, 1), dim3(256), 0, stream,
                           tbf, 256, wqkv_t + (size_t)i * 196608, 256,
                           bqkv + i * 768, nullptr, qkv, 768,
                           (long)0, (long)0, (long)0);

        // ctx path: transpose -> MFMA split-K -> reduce
        hipLaunchKernelGGL(kvt_kernel, dim3(NTOK / 64, NHEAD, BATCH), dim3(256), 0, stream,
                           qkv, kvT);
        hipLaunchKernelGGL(ctx_mfma, dim3(NSPLIT, NHEAD, BATCH), dim3(256), 0, stream,
                           kvT, ctxp, skp);
        hipLaunchKernelGGL(ctxred, dim3(66), dim3(256), 0, stream, ctxp, skp, ctx, Sk);

        // W' = (ctx/Sk) @ Wo (per batch)
        hipLaunchKernelGGL(ctxwo_kernel, dim3(NHEAD, BATCH), dim3(256), 0, stream,
                           ctx, Sk, wo_t + (size_t)i * 65536, wp);

        // o_proj = qs @ W' + bo  (batched over z)
        hipLaunchKernelGGL((gemm_v3<0, 1, 0, 256>), dim3(216, 2, BATCH), dim3(256), 0, stream,
                           qkv, 768, wp, 256, bo + i * 256, nullptr, ob, 256,
                           (long)NTOK * 768, (long)65536, (long)NTOK * 256);

        hipLaunchKernelGGL((ln_kernel<1>), dim3(MTOT), dim3(256), 0, stream,
                           tin, ob, ln1_g + i * 256, ln1_b + i * 256, tbf);

        // FFN (hbf free again: kvT consumed)
        hipLaunchKernelGGL((gemm_v3<2, 1, 0, 256>), dim3(432, 4, 1), dim3(256), 0, stream,
                           tbf, 256, w1_t + (size_t)i * 131072, 256,
                           fb1 + i * 512, nullptr, hbf, 512,
                           (long)0, (long)0, (long)0);
        hipLaunchKernelGGL((gemm_v3<0, 1, 0, 512>), dim3(432, 2, 1), dim3(256), 0, stream,
                           hbf, 512, w2_t + (size_t)i * 131072, 512,
                           fb2 + i * 256, nullptr, ob, 256,
                           (long)0, (long)0, (long)0);
        hipLaunchKernelGGL((ln_kernel<0>), dim3(MTOT), dim3(256), 0, stream,
                           tin, ob, ln2_g + i * 256, ln2_b + i * 256, nullptr);

        // depthwise conv + residual -> tout f32 (+ tbf bf16 except last layer)
        if (i < NLAYERS - 1)
            hipLaunchKernelGGL((posconv_kernel<1>), dim3(576, BATCH), dim3(256), 0, stream,
                               tin, pw + (size_t)i * 6912, pb + i * 256, tout, tbf);
        else
            hipLaunchKernelGGL((posconv_kernel<0>), dim3(576, BATCH), dim3(256), 0, stream,
                               tin, pw + (size_t)i * 6912, pb + i * 256, tout, nullptr);
    }

    // layer 3 wrote tA
    hipLaunchKernelGGL(tr_out, dim3(MTOT / 32, 8), dim3(256), 0, stream, tA, out);
}